// Round 1
// baseline (348.799 us; speedup 1.0000x reference)
//
#include <hip/hip_runtime.h>
#include <hip/hip_bf16.h>

// Problem constants (from reference setup_inputs):
//   B=16, N=4096, C_sp=768, C_fd=512, H=8
// Key simplification: KV length is 1 -> softmax == 1 -> Q/K projections are
// dead code. out[b,n,c] = (freq[b] @ Wv.T + bv) @ Wo.T + bo, broadcast over n.

#define B_   16
#define N_   4096
#define CSP  768
#define CFD  512

// Kernel 1: V[b,j] = bv[j] + sum_i freq[b,i] * Wv[j,i]   (V: [B, CSP])
// grid (B, 6), block 128 -> j = by*128 + tid covers 768
__global__ void __launch_bounds__(128) compute_v(const float* __restrict__ freq,
                                                 const float* __restrict__ Wv,
                                                 const float* __restrict__ bv,
                                                 float* __restrict__ V) {
    const int b   = blockIdx.x;
    const int tid = threadIdx.x;
    const int j   = blockIdx.y * 128 + tid;

    __shared__ float4 sF[CFD / 4];                      // 512 floats = 128 float4
    sF[tid] = ((const float4*)(freq + (size_t)b * CFD))[tid];
    __syncthreads();

    float acc = bv[j];
    const float4* wr = (const float4*)Wv + (size_t)j * (CFD / 4);
#pragma unroll 4
    for (int i = 0; i < CFD / 4; ++i) {
        float4 w = wr[i];
        float4 f = sF[i];
        acc += w.x * f.x + w.y * f.y + w.z * f.z + w.w * f.w;
    }
    V[(size_t)b * CSP + j] = acc;
}

// Kernel 2: O2[b,c] = bo[c] + sum_j V[b,j] * Wo[c,j]    (O2: [B, CSP])
// grid (B, 6), block 128 -> c = by*128 + tid covers 768
__global__ void __launch_bounds__(128) compute_o2(const float* __restrict__ V,
                                                  const float* __restrict__ Wo,
                                                  const float* __restrict__ bo,
                                                  float* __restrict__ O2) {
    const int b   = blockIdx.x;
    const int tid = threadIdx.x;
    const int c   = blockIdx.y * 128 + tid;

    __shared__ float4 sV[CSP / 4];                      // 768 floats = 192 float4
    for (int i = tid; i < CSP / 4; i += 128)
        sV[i] = ((const float4*)(V + (size_t)b * CSP))[i];
    __syncthreads();

    float acc = bo[c];
    const float4* wr = (const float4*)Wo + (size_t)c * (CSP / 4);
#pragma unroll 4
    for (int i = 0; i < CSP / 4; ++i) {
        float4 w = wr[i];
        float4 v = sV[i];
        acc += w.x * v.x + w.y * v.y + w.z * v.z + w.w * v.w;
    }
    O2[(size_t)b * CSP + c] = acc;
}

// Kernel 3: out[b,n,c] = O2[b,c] for all n. Pure broadcast write, 201 MB.
// grid (B, N/ROWS), block 192 (one float4 per thread per row, 192*4=768)
#define ROWS 32
__global__ void __launch_bounds__(192) broadcast_out(const float* __restrict__ O2,
                                                     float* __restrict__ out) {
    const int b     = blockIdx.x;
    const int chunk = blockIdx.y;
    const int tid   = threadIdx.x;

    // Each thread keeps its float4 slice of the O2 row in a register.
    const float4 v = ((const float4*)(O2 + (size_t)b * CSP))[tid];

    float4* dst = (float4*)(out + ((size_t)b * N_ + (size_t)chunk * ROWS) * CSP) + tid;
#pragma unroll
    for (int r = 0; r < ROWS; ++r) {
        dst[(size_t)r * (CSP / 4)] = v;
    }
}

extern "C" void kernel_launch(void* const* d_in, const int* in_sizes, int n_in,
                              void* d_out, int out_size, void* d_ws, size_t ws_size,
                              hipStream_t stream) {
    // Inputs (setup_inputs order):
    // 0: spatial_tokens [B,N,CSP] (dead)
    // 1: freq_token     [B,CFD]
    // 2: Wq (dead)  3: bq (dead)  4: Wk (dead)  5: bk (dead)
    // 6: Wv [CSP,CFD]  7: bv [CSP]  8: Wo [CSP,CSP]  9: bo [CSP]
    const float* freq = (const float*)d_in[1];
    const float* Wv   = (const float*)d_in[6];
    const float* bv   = (const float*)d_in[7];
    const float* Wo   = (const float*)d_in[8];
    const float* bo   = (const float*)d_in[9];
    float* out = (float*)d_out;

    float* V  = (float*)d_ws;            // [B, CSP]
    float* O2 = V + (size_t)B_ * CSP;    // [B, CSP]

    compute_v <<<dim3(B_, CSP / 128), 128, 0, stream>>>(freq, Wv, bv, V);
    compute_o2<<<dim3(B_, CSP / 128), 128, 0, stream>>>(V, Wo, bo, O2);
    broadcast_out<<<dim3(B_, N_ / ROWS), 192, 0, stream>>>(O2, out);
}